// Round 4
// baseline (80.817 us; speedup 1.0000x reference)
//
#include <hip/hip_runtime.h>
#include <math.h>

// WavefunctionEmbedding, fully fused single kernel (NO workspace):
//   out[b,i,2k+0/1] = sum_j amp_ij * {cos,sin}(wn_k * r_ij)
// Block owns ROWS=4 rows: radial histograms in LDS (cubic Lagrange deposit,
// int32 fixed-point ds_add), then in-block contraction against
// cos/sin(wn_k * r_q) via per-thread Chebyshev recurrence.
//
// R16 = R12 shell (512 thr, 3 blocks/CU, deposit arithmetic bit-identical)
// with the block's SERIAL PHASE PATH pipelined. Evidence: R15 halved the
// contraction broadcast reads -> zero effect (uniform-address b128 reads are
// broadcast-cheap; LDS pipe is not critical). R13/R14's constant
// SQ_LDS_BANK_CONFLICT=1,491,240 across merge schemes = deposit-phase
// constant, also not on the critical path. Pipe-throughput sums ~10 us but
// the kernel runs ~20 us: all 768 blocks co-resident -> duration = ONE
// block's serial phase-sum. So overlap the phases:
//   - deposit split into row-pairs A={0,1}, B={2,3}, two half-histograms;
//     after histA's barrier, depositB atomics ISSUE FIRST, then contractA
//     runs while they drain (fire-and-forget ds_add under FMAs).
//   - int->float convert folded into contraction reads (int4 + v_cvt,
//     1/FPSCALE deferred to the single epilogue multiply -- exact until
//     final rounding): removes the convert pass + one barrier.
//   - wavenumber load + Chebyshev seeds hoisted to right after h (off the
//     post-deposit critical path). Seeds saved so contractB reseeds free.
// Contraction decomposition = R12's (2 q-half teams x 256 cols, 4 rows per
// thread): ~30 persistent VGPRs, far from the R13/R14 spill cliff.

#define N_FIXED  1536
#define K_FIXED  256
#define QBINS    256
#define QG       260            // node q represents r = (q-1)*h
#define ROWS     4              // rows per block (768 blocks = 3/CU)
#define RSTRIDE  272            // hist row stride in ints (16B-aligned)
#define NTHREADS 512
#define FPSCALE  4194304.0f     // 2^22 fixed-point scale for hist deposits

typedef __attribute__((ext_vector_type(2))) float f32x2;

// ---------------- fallback: direct kernel (round-1, known-good) ------------
__global__ __launch_bounds__(256) void wf_direct_kernel(
    const float* __restrict__ coords, const unsigned char* __restrict__ mask,
    const float* __restrict__ wavenumbers, float* __restrict__ out, int N, int K)
{
    __shared__ float2 pairs[N_FIXED];
    const int row = blockIdx.x;
    const int b   = row / N;
    const int i   = row - b * N;
    const int t   = threadIdx.x;
    const float* crow = coords + (size_t)b * N * 3;
    const float xi = crow[i*3+0], yi = crow[i*3+1], zi = crow[i*3+2];
    const unsigned char* mrow = mask + (size_t)b * N;
    for (int j = t; j < N; j += blockDim.x) {
        float dx = crow[j*3+0]-xi, dy = crow[j*3+1]-yi, dz = crow[j*3+2]-zi;
        float d2 = fmaf(dx,dx, fmaf(dy,dy, fmaf(dz,dz, 1e-12f)));
        float r  = sqrtf(d2);
        float amp = 0.07957747154594767f / fmaxf(r, 1e-6f);
        if (j == i || mrow[j]) amp = 0.0f;
        pairs[j] = make_float2(r, amp);
    }
    __syncthreads();
    const int k = t;
    const float f = wavenumbers[k] * 0.15915494309189535f;
    float re = 0.0f, im = 0.0f;
    #pragma unroll 4
    for (int j = 0; j < N; ++j) {
        float2 p = pairs[j];
        float x  = __builtin_amdgcn_fractf(p.x * f);
        float c  = __builtin_amdgcn_cosf(x);
        float s  = __builtin_amdgcn_sinf(x);
        re = fmaf(c, p.y, re);
        im = fmaf(s, p.y, im);
    }
    float2* orow = (float2*)out + (size_t)row * K;
    orow[k] = make_float2(re, im);
}

// ---------------- fused: pipelined hist + contraction ----------------------
__global__ __launch_bounds__(NTHREADS) void wf_fused_kernel(
    const float* __restrict__ coords, const unsigned char* __restrict__ mask,
    const float* __restrict__ wavenumbers, float* __restrict__ out, int N)
{
    __shared__ int   histA[2 * RSTRIDE];           // rows 0,1  (2.2 KB)
    __shared__ int   histB[2 * RSTRIDE];           // rows 2,3  (2.2 KB)
    __shared__ float red[8];
    __shared__ f32x2 merge[ROWS * K_FIXED];        // 8 KB qh=1 partials

    const int i0 = blockIdx.x * ROWS;      // first global row of this block
    const int b  = i0 / N;                 // N % ROWS == 0 -> block within b
    const int t  = threadIdx.x;

    const float* crow = coords + (size_t)b * N * 3;
    const unsigned char* mrow = mask + (size_t)b * N;

    // ---- rmax over THIS BATCH only (h is per-block-consistent) ----
    float m = 0.0f;
    #pragma unroll
    for (int s = 0; s < N_FIXED / NTHREADS; ++s) {
        const int p = t + NTHREADS * s;
        float x = crow[3*p], y = crow[3*p+1], z = crow[3*p+2];
        m = fmaxf(m, fmaf(x,x, fmaf(y,y, z*z)));
    }
    #pragma unroll
    for (int off = 32; off >= 1; off >>= 1)
        m = fmaxf(m, __shfl_down(m, off, 64));
    if ((t & 63) == 0) red[t >> 6] = m;
    for (int a = t; a < 2 * RSTRIDE; a += NTHREADS) { histA[a] = 0; histB[a] = 0; }
    __syncthreads();
    float mm = red[0];
    #pragma unroll
    for (int w = 1; w < 8; ++w) mm = fmaxf(mm, red[w]);
    const float rmax = 2.0005f * sqrtf(mm) + 1e-3f;   // r_ij <= 2 max|c|
    const float h    = rmax / (float)QBINS;           // => u = r/h < 256
    const float inv_h = 1.0f / h;

    // ---- contraction seeds, hoisted (depend only on h + wavenumbers) ----
    const int qh   = t >> 8;               // q-half team 0/1
    const int c    = t & 255;              // owned column
    const int gbeg = qh ? 33 : 0;          // groups of 4 q-nodes
    const int gend = qh ? 65 : 33;         // 65 groups cover q 0..259
    const int qs   = gbeg * 4;

    const float xr  = wavenumbers[c] * 0.15915494309189535f * h;
    const float k2s = 2.0f * __builtin_amdgcn_cosf(__builtin_amdgcn_fractf(xr));
    const f32x2 k2  = {k2s, k2s};
    const float aarg = __builtin_amdgcn_fractf((float)(qs - 1) * xr);
    const float barg = __builtin_amdgcn_fractf((float)qs * xr);
    const f32x2 wa_s = {__builtin_amdgcn_cosf(aarg), __builtin_amdgcn_sinf(aarg)};
    const f32x2 wb_s = {__builtin_amdgcn_cosf(barg), __builtin_amdgcn_sinf(barg)};

    // ---- deposit macro body (bit-identical arithmetic to R12) ----
    const int il0 = i0 - b * N;            // local i of row 0
#define DEPOSIT_PAIR(HIST, ROW0)                                              \
    {                                                                         \
        const float c0x = crow[3*(il0+(ROW0))],                               \
                    c0y = crow[3*(il0+(ROW0))+1],                             \
                    c0z = crow[3*(il0+(ROW0))+2];                             \
        const float c1x = crow[3*(il0+(ROW0)+1)],                             \
                    c1y = crow[3*(il0+(ROW0)+1)+1],                           \
                    c1z = crow[3*(il0+(ROW0)+1)+2];                           \
        _Pragma("unroll")                                                     \
        for (int s = 0; s < N_FIXED / NTHREADS; ++s) {                        \
            const int j = t + NTHREADS * s;                                   \
            const float xj = crow[3*j], yj = crow[3*j+1], zj = crow[3*j+2];   \
            const bool masked = (mrow[j] != 0);                               \
            _Pragma("unroll")                                                 \
            for (int r = 0; r < 2; ++r) {                                     \
                const float cxr = r ? c1x : c0x;                              \
                const float cyr = r ? c1y : c0y;                              \
                const float czr = r ? c1z : c0z;                              \
                float dx = xj - cxr;                                          \
                float dy = yj - cyr;                                          \
                float dz = zj - czr;                                          \
                float d2 = fmaf(dx,dx, fmaf(dy,dy, fmaf(dz,dz, 1e-12f)));     \
                float rsq = __builtin_amdgcn_rsqf(d2);                        \
                float amp = 0.07957747154594767f * rsq;                       \
                if (j == il0 + (ROW0) + r || masked) amp = 0.0f;              \
                float u  = d2 * rsq * inv_h;                                  \
                float qf = floorf(u);                                         \
                int   q0 = (int)qf;                                           \
                float tt = u - qf;                                            \
                float as6 = amp * (FPSCALE * (1.0f/6.0f));                    \
                float as2 = amp * (FPSCALE * 0.5f);                           \
                float tm1 = tt + 1.0f, t1 = tt - 1.0f, t2 = tt - 2.0f;        \
                float p  = tt  * t1;                                          \
                float qq = tm1 * t2;                                          \
                int w0 = (int)(-(p  * t2)  * as6);                            \
                int w1 = (int)( (qq * t1)  * as2);                            \
                int w2 = (int)(-(qq * tt)  * as2);                            \
                int w3 = (int)( (p  * tm1) * as6);                            \
                int* hb = &(HIST)[r * RSTRIDE + q0];                          \
                atomicAdd(hb + 0, w0);                                        \
                atomicAdd(hb + 1, w1);                                        \
                atomicAdd(hb + 2, w2);                                        \
                atomicAdd(hb + 3, w3);                                        \
            }                                                                 \
        }                                                                     \
    }

    // ---- contraction macro: int4 read + cvt, FMA into 2 row-accs ----
#define CONTRACT_PAIR(HIST, ACC0, ACC1, WA, WB)                               \
    {                                                                         \
        _Pragma("unroll 2")                                                   \
        for (int g = gbeg; g < gend; ++g) {                                   \
            const int q0 = g * 4;                                             \
            const int4 ia = *(const int4*)&(HIST)[0 * RSTRIDE + q0];          \
            const int4 ib = *(const int4*)&(HIST)[1 * RSTRIDE + q0];          \
            const float ra[4] = {(float)ia.x, (float)ia.y,                    \
                                 (float)ia.z, (float)ia.w};                   \
            const float rb[4] = {(float)ib.x, (float)ib.y,                    \
                                 (float)ib.z, (float)ib.w};                   \
            _Pragma("unroll")                                                 \
            for (int d = 0; d < 4; ++d) {                                     \
                const f32x2 sa = {ra[d], ra[d]};                              \
                const f32x2 sb = {rb[d], rb[d]};                              \
                ACC0 = __builtin_elementwise_fma(sa, WA, ACC0);               \
                ACC1 = __builtin_elementwise_fma(sb, WA, ACC1);               \
                const f32x2 wn = __builtin_elementwise_fma(k2, WB, -WA);      \
                WA = WB; WB = wn;                                             \
            }                                                                 \
        }                                                                     \
    }

    f32x2 acc0 = {0.f,0.f}, acc1 = {0.f,0.f};   // rows 0,1
    f32x2 acc2 = {0.f,0.f}, acc3 = {0.f,0.f};   // rows 2,3

    // ---- phase A deposit ----
    DEPOSIT_PAIR(histA, 0)
    __syncthreads();                       // histA complete

    // ---- phase B deposit (atomics issue first), then contract A ----
    DEPOSIT_PAIR(histB, 2)
    {
        f32x2 wa = wa_s, wb = wb_s;
        CONTRACT_PAIR(histA, acc0, acc1, wa, wb)
    }
    __syncthreads();                       // histB complete (+A reads done)

    // ---- contract B ----
    {
        f32x2 wa = wa_s, wb = wb_s;
        CONTRACT_PAIR(histB, acc2, acc3, wa, wb)
    }

    // ---- merge q-half teams, scale by 1/FPSCALE, store ----
    if (qh == 1) {
        merge[0 * K_FIXED + c] = acc0;
        merge[1 * K_FIXED + c] = acc1;
        merge[2 * K_FIXED + c] = acc2;
        merge[3 * K_FIXED + c] = acc3;
    }
    __syncthreads();
    if (qh == 0) {
        const float invS = 1.0f / FPSCALE;
        const f32x2 sS = {invS, invS};
        const f32x2 v0 = (acc0 + merge[0 * K_FIXED + c]) * sS;
        const f32x2 v1 = (acc1 + merge[1 * K_FIXED + c]) * sS;
        const f32x2 v2 = (acc2 + merge[2 * K_FIXED + c]) * sS;
        const f32x2 v3 = (acc3 + merge[3 * K_FIXED + c]) * sS;
        ((float2*)out)[(size_t)(i0 + 0) * K_FIXED + c] = make_float2(v0.x, v0.y);
        ((float2*)out)[(size_t)(i0 + 1) * K_FIXED + c] = make_float2(v1.x, v1.y);
        ((float2*)out)[(size_t)(i0 + 2) * K_FIXED + c] = make_float2(v2.x, v2.y);
        ((float2*)out)[(size_t)(i0 + 3) * K_FIXED + c] = make_float2(v3.x, v3.y);
    }
#undef DEPOSIT_PAIR
#undef CONTRACT_PAIR
}

extern "C" void kernel_launch(void* const* d_in, const int* in_sizes, int n_in,
                              void* d_out, int out_size, void* d_ws, size_t ws_size,
                              hipStream_t stream) {
    const float* coords          = (const float*)d_in[0];
    const unsigned char* mask    = (const unsigned char*)d_in[1];
    const float* wavenumbers     = (const float*)d_in[2];
    float* out                   = (float*)d_out;

    const int K  = in_sizes[2];
    const int BN = in_sizes[0] / 3;        // B*N
    const int N  = N_FIXED;

    if (K != K_FIXED || BN % N != 0 || (N % ROWS) != 0 ||
        (N % NTHREADS) != 0) {
        wf_direct_kernel<<<BN, K, 0, stream>>>(coords, mask, wavenumbers, out, N, K);
        return;
    }

    wf_fused_kernel<<<BN / ROWS, NTHREADS, 0, stream>>>(coords, mask,
                                                        wavenumbers, out, N);
}

// Round 5
// 77.026 us; speedup vs baseline: 1.0492x; 1.0492x over previous
//
#include <hip/hip_runtime.h>
#include <math.h>

// WavefunctionEmbedding, fully fused single kernel (NO workspace):
//   out[b,i,2k+0/1] = sum_j amp_ij * {cos,sin}(wn_k * r_ij)
// Block owns ROWS=4 rows: radial histograms in LDS (cubic Lagrange deposit,
// int32 fixed-point ds_add), then in-block contraction against
// cos/sin(wn_k * r_q) via per-thread Chebyshev recurrence.
//
// R17 = R15 (equal-best with R12: 74.2-75.7 us total, ~20 us kernel) plus
// ONLY the two provably-bitwise-neutral pieces of R16:
//   (a) int->float convert folded into the contraction reads (int4 +
//       v_cvt_f32_i32), with the 1/FPSCALE scale deferred to the epilogue.
//       FPSCALE = 2^22 -> the deferred scale is a pure exponent shift, EXACT;
//       (float)int is the same cvt R12's convert pass did. Deletes the
//       convert pass and one full barrier. Output bitwise identical.
//   (b) wavenumbers[] loads hoisted to kernel entry (cold-load latency off
//       the post-deposit critical path; +2 VGPRs, seeds stay post-deposit
//       so allocator pressure matches R15 -- the R13/R14 spill lesson).
// R16 post-mortem (REGRESSED 80.8): ds_add and ds_read share lgkmcnt and
// complete in order, so a waitcnt protecting a contractA read drains ALL of
// depositB's atomics -- deposit/contract overlap is structurally impossible
// for LDS-atomic producers feeding LDS readers. Deposit stays the single
// 4-row pass, bit-identical to R12.

#define N_FIXED  1536
#define K_FIXED  256
#define QBINS    256
#define QG       260            // node q represents r = (q-1)*h
#define ROWS     4              // rows per block (768 blocks = 3/CU)
#define RSTRIDE  272            // hist row stride in ints (16B-aligned)
#define NTHREADS 512
#define FPSCALE  4194304.0f     // 2^22 fixed-point scale for hist deposits

typedef __attribute__((ext_vector_type(2))) float f32x2;

// ---------------- fallback: direct kernel (round-1, known-good) ------------
__global__ __launch_bounds__(256) void wf_direct_kernel(
    const float* __restrict__ coords, const unsigned char* __restrict__ mask,
    const float* __restrict__ wavenumbers, float* __restrict__ out, int N, int K)
{
    __shared__ float2 pairs[N_FIXED];
    const int row = blockIdx.x;
    const int b   = row / N;
    const int i   = row - b * N;
    const int t   = threadIdx.x;
    const float* crow = coords + (size_t)b * N * 3;
    const float xi = crow[i*3+0], yi = crow[i*3+1], zi = crow[i*3+2];
    const unsigned char* mrow = mask + (size_t)b * N;
    for (int j = t; j < N; j += blockDim.x) {
        float dx = crow[j*3+0]-xi, dy = crow[j*3+1]-yi, dz = crow[j*3+2]-zi;
        float d2 = fmaf(dx,dx, fmaf(dy,dy, fmaf(dz,dz, 1e-12f)));
        float r  = sqrtf(d2);
        float amp = 0.07957747154594767f / fmaxf(r, 1e-6f);
        if (j == i || mrow[j]) amp = 0.0f;
        pairs[j] = make_float2(r, amp);
    }
    __syncthreads();
    const int k = t;
    const float f = wavenumbers[k] * 0.15915494309189535f;
    float re = 0.0f, im = 0.0f;
    #pragma unroll 4
    for (int j = 0; j < N; ++j) {
        float2 p = pairs[j];
        float x  = __builtin_amdgcn_fractf(p.x * f);
        float c  = __builtin_amdgcn_cosf(x);
        float s  = __builtin_amdgcn_sinf(x);
        re = fmaf(c, p.y, re);
        im = fmaf(s, p.y, im);
    }
    float2* orow = (float2*)out + (size_t)row * K;
    orow[k] = make_float2(re, im);
}

// ---------------- fused: hist + row-pair/q-half contraction ----------------
__global__ __launch_bounds__(NTHREADS) void wf_fused_kernel(
    const float* __restrict__ coords, const unsigned char* __restrict__ mask,
    const float* __restrict__ wavenumbers, float* __restrict__ out, int N)
{
    __shared__ int   hist[ROWS * RSTRIDE];         // 4.25 KB, r-major, int
    __shared__ float red[8];
    __shared__ f32x2 merge[ROWS * K_FIXED];        // 8 KB qh=1 partials

    const int i0 = blockIdx.x * ROWS;      // first global row of this block
    const int b  = i0 / N;                 // N % ROWS == 0 -> block within b
    const int t  = threadIdx.x;

    // contraction identity, computed early for the hoisted loads
    const int team = t >> 7;               // 0..3
    const int p    = team >> 1;            // row-pair 0 (rows 0,1) / 1 (2,3)
    const int qh   = team & 1;             // q-half
    const int c    = t & 127;              // first owned column

    // (b) hoisted cold global loads -- L2-warm by contraction time
    const float wnc0 = wavenumbers[c];
    const float wnc1 = wavenumbers[c + 128];

    const float* crow = coords + (size_t)b * N * 3;
    const unsigned char* mrow = mask + (size_t)b * N;

    // ---- rmax over THIS BATCH only (h is per-block-consistent) ----
    float m = 0.0f;
    #pragma unroll
    for (int s = 0; s < N_FIXED / NTHREADS; ++s) {
        const int pp = t + NTHREADS * s;
        float x = crow[3*pp], y = crow[3*pp+1], z = crow[3*pp+2];
        m = fmaxf(m, fmaf(x,x, fmaf(y,y, z*z)));
    }
    #pragma unroll
    for (int off = 32; off >= 1; off >>= 1)
        m = fmaxf(m, __shfl_down(m, off, 64));
    if ((t & 63) == 0) red[t >> 6] = m;
    for (int a = t; a < ROWS * RSTRIDE; a += NTHREADS) hist[a] = 0;
    __syncthreads();
    float mm = red[0];
    #pragma unroll
    for (int w = 1; w < 8; ++w) mm = fmaxf(mm, red[w]);
    const float rmax = 2.0005f * sqrtf(mm) + 1e-3f;   // r_ij <= 2 max|c|
    const float h    = rmax / (float)QBINS;           // => u = r/h < 256
    const float inv_h = 1.0f / h;

    // ---- histograms: each j loaded once, deposit into all ROWS rows ----
    const int il0 = i0 - b * N;            // local i of row 0
    float cx[ROWS], cy[ROWS], cz[ROWS];
    #pragma unroll
    for (int r = 0; r < ROWS; ++r) {
        cx[r] = crow[3*(il0+r)];
        cy[r] = crow[3*(il0+r)+1];
        cz[r] = crow[3*(il0+r)+2];
    }

    #pragma unroll
    for (int s = 0; s < N_FIXED / NTHREADS; ++s) {
        const int j = t + NTHREADS * s;
        const float xj = crow[3*j], yj = crow[3*j+1], zj = crow[3*j+2];
        const bool masked = (mrow[j] != 0);
        #pragma unroll
        for (int r = 0; r < ROWS; ++r) {
            float dx = xj - cx[r];
            float dy = yj - cy[r];
            float dz = zj - cz[r];
            float d2 = fmaf(dx,dx, fmaf(dy,dy, fmaf(dz,dz, 1e-12f)));
            float rsq = __builtin_amdgcn_rsqf(d2);     // 1/r, r >= 1e-6
            float amp = 0.07957747154594767f * rsq;    // 1/(4 pi r)
            if (j == il0 + r || masked) amp = 0.0f;

            float u  = d2 * rsq * inv_h;               // r/h, in [0,256)
            float qf = floorf(u);
            int   q0 = (int)qf;                        // 0..255, no clamp
            float tt = u - qf;
            // Lagrange cubic through nodes {-1,0,1,2} at offset tt in [0,1)
            float as6 = amp * (FPSCALE * (1.0f/6.0f));
            float as2 = amp * (FPSCALE * 0.5f);
            float tm1 = tt + 1.0f, t1 = tt - 1.0f, t2 = tt - 2.0f;
            float pg  = tt  * t1;                      // t(t-1)
            float qq  = tm1 * t2;                      // (t+1)(t-2)
            int w0 = (int)(-(pg * t2)  * as6);         // truncating cvt
            int w1 = (int)( (qq * t1)  * as2);
            int w2 = (int)(-(qq * tt)  * as2);
            int w3 = (int)( (pg * tm1) * as6);
            int* hb = &hist[r * RSTRIDE + q0];
            atomicAdd(hb + 0, w0);                     // native ds_add
            atomicAdd(hb + 1, w1);
            atomicAdd(hb + 2, w2);
            atomicAdd(hb + 3, w3);
        }
    }
    __syncthreads();
    // (a) no convert pass, no extra barrier: contraction reads int directly

    // ---- contraction: 4 teams of 128 = (row-pair p, q-half qh);
    //      thread owns cols c and c+128 for rows 2p, 2p+1. ----
    const int gbeg = qh ? 33 : 0;          // groups of 4 q-nodes
    const int gend = qh ? 65 : 33;         // 65 groups cover q 0..259
    const int qs   = gbeg * 4;

    // theta (revolutions per node) = wn * h / 2pi; per-column Chebyshev
    const float xr0 = wnc0 * 0.15915494309189535f * h;
    const float xr1 = wnc1 * 0.15915494309189535f * h;
    const float k2s0 = 2.0f * __builtin_amdgcn_cosf(__builtin_amdgcn_fractf(xr0));
    const float k2s1 = 2.0f * __builtin_amdgcn_cosf(__builtin_amdgcn_fractf(xr1));
    const f32x2 k20 = {k2s0, k2s0};
    const f32x2 k21 = {k2s1, k2s1};
    // Chebyshev seeds: w_a = cis((qs-1)*th), w_b = cis(qs*th); (cos,sin)
    const float a0arg = __builtin_amdgcn_fractf((float)(qs - 1) * xr0);
    const float b0arg = __builtin_amdgcn_fractf((float)qs * xr0);
    const float a1arg = __builtin_amdgcn_fractf((float)(qs - 1) * xr1);
    const float b1arg = __builtin_amdgcn_fractf((float)qs * xr1);
    f32x2 wa0 = {__builtin_amdgcn_cosf(a0arg), __builtin_amdgcn_sinf(a0arg)};
    f32x2 wb0 = {__builtin_amdgcn_cosf(b0arg), __builtin_amdgcn_sinf(b0arg)};
    f32x2 wa1 = {__builtin_amdgcn_cosf(a1arg), __builtin_amdgcn_sinf(a1arg)};
    f32x2 wb1 = {__builtin_amdgcn_cosf(b1arg), __builtin_amdgcn_sinf(b1arg)};

    // acc[row-in-pair][owned-col]; named scalars only (raw, scale deferred)
    f32x2 a00 = {0.f,0.f}, a01 = {0.f,0.f};   // col c  : rows 2p, 2p+1
    f32x2 a10 = {0.f,0.f}, a11 = {0.f,0.f};   // col c+128

    const int r0off = (2*p + 0) * RSTRIDE;
    const int r1off = (2*p + 1) * RSTRIDE;

    #pragma unroll 2
    for (int g = gbeg; g < gend; ++g) {
        const int q0 = g * 4;
        const int4 ia = *(const int4*)&hist[r0off + q0];  // ds_read_b128
        const int4 ib = *(const int4*)&hist[r1off + q0];
        const float ra[4] = {(float)ia.x, (float)ia.y, (float)ia.z, (float)ia.w};
        const float rb[4] = {(float)ib.x, (float)ib.y, (float)ib.z, (float)ib.w};
        #pragma unroll
        for (int d = 0; d < 4; ++d) {
            const f32x2 sa = {ra[d], ra[d]};
            const f32x2 sb = {rb[d], rb[d]};
            // packed acc: v_pk_fma_f32 (splat h, multiply (cos,sin))
            a00 = __builtin_elementwise_fma(sa, wa0, a00);
            a01 = __builtin_elementwise_fma(sb, wa0, a01);
            a10 = __builtin_elementwise_fma(sa, wa1, a10);
            a11 = __builtin_elementwise_fma(sb, wa1, a11);
            // packed Chebyshev step: w_{q+1} = k2*w_q - w_{q-1}
            const f32x2 wn0 = __builtin_elementwise_fma(k20, wb0, -wa0);
            const f32x2 wn1 = __builtin_elementwise_fma(k21, wb1, -wa1);
            wa0 = wb0; wb0 = wn0;
            wa1 = wb1; wb1 = wn1;
        }
    }

    // ---- merge: qh=1 teams store raw partials; qh=0 adds, scales by
    //      invS = 2^-22 (exact exponent shift), writes out ----
    if (qh == 1) {
        merge[(2*p + 0) * K_FIXED + c]       = a00;
        merge[(2*p + 1) * K_FIXED + c]       = a01;
        merge[(2*p + 0) * K_FIXED + c + 128] = a10;
        merge[(2*p + 1) * K_FIXED + c + 128] = a11;
    }
    __syncthreads();
    if (qh == 0) {
        const float invS = 1.0f / FPSCALE;
        const f32x2 sS = {invS, invS};
        const f32x2 v00 = (a00 + merge[(2*p + 0) * K_FIXED + c])       * sS;
        const f32x2 v01 = (a01 + merge[(2*p + 1) * K_FIXED + c])       * sS;
        const f32x2 v10 = (a10 + merge[(2*p + 0) * K_FIXED + c + 128]) * sS;
        const f32x2 v11 = (a11 + merge[(2*p + 1) * K_FIXED + c + 128]) * sS;
        float2* orow0 = (float2*)out + (size_t)(i0 + 2*p + 0) * K_FIXED;
        float2* orow1 = (float2*)out + (size_t)(i0 + 2*p + 1) * K_FIXED;
        orow0[c]       = make_float2(v00.x, v00.y);
        orow1[c]       = make_float2(v01.x, v01.y);
        orow0[c + 128] = make_float2(v10.x, v10.y);
        orow1[c + 128] = make_float2(v11.x, v11.y);
    }
}

extern "C" void kernel_launch(void* const* d_in, const int* in_sizes, int n_in,
                              void* d_out, int out_size, void* d_ws, size_t ws_size,
                              hipStream_t stream) {
    const float* coords          = (const float*)d_in[0];
    const unsigned char* mask    = (const unsigned char*)d_in[1];
    const float* wavenumbers     = (const float*)d_in[2];
    float* out                   = (float*)d_out;

    const int K  = in_sizes[2];
    const int BN = in_sizes[0] / 3;        // B*N
    const int N  = N_FIXED;

    if (K != K_FIXED || BN % N != 0 || (N % ROWS) != 0 ||
        (N % NTHREADS) != 0) {
        wf_direct_kernel<<<BN, K, 0, stream>>>(coords, mask, wavenumbers, out, N, K);
        return;
    }

    wf_fused_kernel<<<BN / ROWS, NTHREADS, 0, stream>>>(coords, mask,
                                                        wavenumbers, out, N);
}